// Round 3
// baseline (2100.075 us; speedup 1.0000x reference)
//
#include <hip/hip_runtime.h>
#include <math.h>

#define N_NODES 16384
#define DIM 128
#define HC 384          // HEADS * C
#define NEG_SLOPE 0.2f
#define KNN 16
#define KN_CAP 8

// ---------------- kernel 0: row squared norms ----------------
__global__ __launch_bounds__(256) void sq_kernel(const float* __restrict__ x,
                                                 float* __restrict__ sq) {
  const int wv = threadIdx.x >> 6;
  const int lane = threadIdx.x & 63;
  const int row = blockIdx.x * 4 + wv;
  const float2 v = *(const float2*)&x[row * DIM + lane * 2];
  float s = v.x * v.x + v.y * v.y;
  #pragma unroll
  for (int off = 32; off > 0; off >>= 1) s += __shfl_down(s, off);
  if (lane == 0) sq[row] = s;
}

// ---------------- kernel 1: xl = x@Wl, xr = x@Wr ----------------
__global__ __launch_bounds__(256) void gemm_xw(const float* __restrict__ x,
                                               const float* __restrict__ Wl,
                                               const float* __restrict__ Wr,
                                               float* __restrict__ xl,
                                               float* __restrict__ xr) {
  __shared__ __align__(16) float As[64 * 132];
  __shared__ __align__(16) float WsT[128 * 68];
  const float* __restrict__ W = blockIdx.z ? Wr : Wl;
  float* __restrict__ o = blockIdx.z ? xr : xl;
  const int rowbase = blockIdx.x * 64;
  const int cb = blockIdx.y * 128;
  const int tid = threadIdx.x;
  const int tx = tid & 15, ty = tid >> 4;

  #pragma unroll
  for (int i = 0; i < 8; i++) {
    int f = i * 256 + tid;
    int r = f >> 5, k4 = f & 31;
    *(float4*)&As[r * 132 + k4 * 4] = *(const float4*)&x[(rowbase + r) * DIM + k4 * 4];
  }

  float acc[4][8];
  #pragma unroll
  for (int i = 0; i < 4; i++)
    #pragma unroll
    for (int j = 0; j < 8; j++) acc[i][j] = 0.f;

  for (int kh = 0; kh < 2; kh++) {
    __syncthreads();
    #pragma unroll
    for (int i = 0; i < 8; i++) {
      int f = i * 256 + tid;
      int kk = f >> 5, cf4 = f & 31;
      float4 v = *(const float4*)&W[(kh * 64 + kk) * HC + cb + cf4 * 4];
      WsT[(cf4 * 4 + 0) * 68 + kk] = v.x;
      WsT[(cf4 * 4 + 1) * 68 + kk] = v.y;
      WsT[(cf4 * 4 + 2) * 68 + kk] = v.z;
      WsT[(cf4 * 4 + 3) * 68 + kk] = v.w;
    }
    __syncthreads();
    #pragma unroll
    for (int k4 = 0; k4 < 16; k4++) {
      float4 b[8];
      #pragma unroll
      for (int j = 0; j < 8; j++)
        b[j] = *(const float4*)&WsT[(tx + 16 * j) * 68 + k4 * 4];
      #pragma unroll
      for (int i = 0; i < 4; i++) {
        float4 a = *(const float4*)&As[(ty * 4 + i) * 132 + kh * 64 + k4 * 4];
        #pragma unroll
        for (int j = 0; j < 8; j++) {
          acc[i][j] += a.x * b[j].x;
          acc[i][j] += a.y * b[j].y;
          acc[i][j] += a.z * b[j].z;
          acc[i][j] += a.w * b[j].w;
        }
      }
    }
  }
  #pragma unroll
  for (int i = 0; i < 4; i++)
    #pragma unroll
    for (int j = 0; j < 8; j++)
      o[(rowbase + ty * 4 + i) * HC + cb + tx + 16 * j] = acc[i][j];
}

// ---------------- kernel 2: fused pairwise-dist + top-16 ----------------
// 512 thr (8 waves). BM=64 rows, BN=128 cols/tile, K staged in two 64-halves
// (stride 68, k4 in [0,16) -> max float offset 63 < 68: no overlap).
// A-operand via wave-uniform scalar loads; LDS serves only B.
__global__ __launch_bounds__(512, 4) void knn_kernel(const float* __restrict__ x,
                                                     const float* __restrict__ sq,
                                                     int* __restrict__ idxo) {
  __shared__ __align__(16) float Bs[128 * 68];  // 34816 B
  __shared__ float Ss[128];
  __shared__ float Srow[64];
  __shared__ float Thr[64];
  __shared__ int Cnt[64];
  __shared__ float Topd[KNN][64];     // transposed: merge lanes stride-1
  __shared__ int   Topi[KNN][64];
  __shared__ float Bufd[KN_CAP][64];
  __shared__ int   Bufi[KN_CAP][64];
  __shared__ int Flag;

  const int tid = threadIdx.x;
  const int lane = tid & 63;
  const int wvu = __builtin_amdgcn_readfirstlane(tid >> 6);  // uniform wave id
  const int rowbase = blockIdx.x * 64;
  const float* __restrict__ arow = x + (size_t)(rowbase + wvu * 8) * DIM;

  if (tid < 64) {
    Srow[tid] = sq[rowbase + tid];
    Thr[tid] = __builtin_inff();
    Cnt[tid] = 0;
  }
  if (tid == 0) Flag = 0;

  // persistent per-merge-thread (tid<64) top-k state
  int kcnt = 0, wj = 0, wpos = 0;
  float wd = __builtin_inff();

  for (int tile = 0; tile < N_NODES / 128; tile++) {
    const int colbase = tile * 128;
    if (tid < 128) Ss[tid] = sq[colbase + tid];

    float acc[8][2];
    #pragma unroll
    for (int i = 0; i < 8; i++) { acc[i][0] = 0.f; acc[i][1] = 0.f; }

    for (int kh = 0; kh < 2; kh++) {
      #pragma unroll
      for (int i = 0; i < 4; i++) {
        int f = i * 512 + tid;           // [0,2048)
        int c = f >> 4, k4 = f & 15;     // c in [0,128), k4 in [0,16)
        *(float4*)&Bs[c * 68 + k4 * 4] =
            *(const float4*)&x[(colbase + c) * DIM + kh * 64 + k4 * 4];
      }
      __syncthreads();
      const int koff = kh * 64;
      #pragma unroll
      for (int k4 = 0; k4 < 16; k4++) {
        const float4 b0 = *(const float4*)&Bs[lane * 68 + k4 * 4];
        const float4 b1 = *(const float4*)&Bs[(lane + 64) * 68 + k4 * 4];
        #pragma unroll
        for (int i = 0; i < 8; i++) {
          const float4 a = *(const float4*)(arow + i * DIM + koff + k4 * 4);  // uniform -> s_load
          acc[i][0] += a.x * b0.x; acc[i][0] += a.y * b0.y;
          acc[i][0] += a.z * b0.z; acc[i][0] += a.w * b0.w;
          acc[i][1] += a.x * b1.x; acc[i][1] += a.y * b1.y;
          acc[i][1] += a.z * b1.z; acc[i][1] += a.w * b1.w;
        }
      }
      __syncthreads();
    }

    // distances, mark candidates
    unsigned int pend = 0;
    #pragma unroll
    for (int i = 0; i < 8; i++) {
      const int r = wvu * 8 + i;
      const int rg = rowbase + r;
      const float sr = Srow[r];
      #pragma unroll
      for (int j = 0; j < 2; j++) {
        const int cg = colbase + lane + 64 * j;
        float d = sr + Ss[lane + 64 * j] - 2.f * acc[i][j];
        acc[i][j] = d;
        if (cg != rg) pend |= (1u << (i * 2 + j));
      }
    }

    // push/merge rounds
    while (true) {
      #pragma unroll
      for (int i = 0; i < 8; i++) {
        const float t = Thr[wvu * 8 + i];
        #pragma unroll
        for (int j = 0; j < 2; j++) {
          const unsigned int b = 1u << (i * 2 + j);
          if ((pend & b) && !(acc[i][j] <= t)) pend &= ~b;
        }
      }
      if (tid == 0) Flag = 0;
      __syncthreads();  // B1
      if (pend) {
        #pragma unroll
        for (int i = 0; i < 8; i++) {
          #pragma unroll
          for (int j = 0; j < 2; j++) {
            const unsigned int b = 1u << (i * 2 + j);
            if (pend & b) {
              const int r = wvu * 8 + i;
              const int slot = atomicAdd(&Cnt[r], 1);
              if (slot < KN_CAP) {
                Bufd[slot][r] = acc[i][j];
                Bufi[slot][r] = colbase + lane + 64 * j;
                pend &= ~b;
              }
            }
          }
        }
        if (pend) Flag = 1;
      }
      __syncthreads();  // B2
      const int fl = Flag;
      if (tid < 64) {
        int nn = Cnt[tid]; if (nn > KN_CAP) nn = KN_CAP;
        for (int e = 0; e < nn; e++) {
          const float d = Bufd[e][tid];
          const int jj = Bufi[e][tid];
          bool rescan = false;
          if (kcnt < KNN) {
            Topd[kcnt][tid] = d; Topi[kcnt][tid] = jj; kcnt++;
            rescan = (kcnt == KNN);
          } else if (d < wd || (d == wd && jj < wj)) {
            Topd[wpos][tid] = d; Topi[wpos][tid] = jj;
            rescan = true;
          }
          if (rescan) {
            wd = Topd[0][tid]; wj = Topi[0][tid]; wpos = 0;
            #pragma unroll
            for (int e2 = 1; e2 < KNN; e2++) {
              const float dd = Topd[e2][tid];
              const int j2 = Topi[e2][tid];
              if (dd > wd || (dd == wd && j2 > wj)) { wd = dd; wj = j2; wpos = e2; }
            }
            Thr[tid] = wd;
          }
        }
        Cnt[tid] = 0;
      }
      __syncthreads();  // B3
      if (fl == 0) break;
    }
  }

  if (tid < 64) {
    #pragma unroll
    for (int e = 0; e < KNN; e++)
      idxo[(rowbase + tid) * KNN + e] = Topi[e][tid];
  }
}

// ---------------- kernel 3: GATv2 attention epilogue ----------------
__global__ __launch_bounds__(64) void attn_kernel(const float* __restrict__ xl,
                                                  const float* __restrict__ xr,
                                                  const float* __restrict__ att,
                                                  const float* __restrict__ bias,
                                                  const int* __restrict__ idxo,
                                                  float* __restrict__ out) {
  const int n = blockIdx.x;
  const int lane = threadIdx.x;
  __shared__ int nb[KNN];
  if (lane < KNN) nb[lane] = idxo[n * KNN + lane];
  __syncthreads();
  float o0 = 0.f, o1 = 0.f;
  #pragma unroll
  for (int h = 0; h < 3; h++) {
    const float r0 = xr[n * HC + h * 128 + lane];
    const float r1 = xr[n * HC + h * 128 + 64 + lane];
    const float a0 = att[h * 128 + lane];
    const float a1 = att[h * 128 + 64 + lane];
    float v0[KNN], v1[KNN], e[KNN];
    #pragma unroll
    for (int kk = 0; kk < KNN; kk++) {
      const float* xp = &xl[(size_t)nb[kk] * HC + h * 128];
      float x0 = xp[lane], x1 = xp[64 + lane];
      v0[kk] = x0; v1[kk] = x1;
      float g0 = x0 + r0; g0 = g0 >= 0.f ? g0 : NEG_SLOPE * g0;
      float g1 = x1 + r1; g1 = g1 >= 0.f ? g1 : NEG_SLOPE * g1;
      float p = a0 * g0 + a1 * g1;
      #pragma unroll
      for (int off = 32; off > 0; off >>= 1) p += __shfl_xor(p, off);
      e[kk] = p;
    }
    float m = e[0];
    #pragma unroll
    for (int kk = 1; kk < KNN; kk++) m = fmaxf(m, e[kk]);
    float s = 0.f;
    float w[KNN];
    #pragma unroll
    for (int kk = 0; kk < KNN; kk++) { w[kk] = expf(e[kk] - m); s += w[kk]; }
    #pragma unroll
    for (int kk = 0; kk < KNN; kk++) {
      float al = w[kk] / s;
      o0 += al * v0[kk];
      o1 += al * v1[kk];
    }
  }
  out[n * 128 + lane]      = o0 / 3.f + bias[lane];
  out[n * 128 + 64 + lane] = o1 / 3.f + bias[64 + lane];
}

extern "C" void kernel_launch(void* const* d_in, const int* in_sizes, int n_in,
                              void* d_out, int out_size, void* d_ws, size_t ws_size,
                              hipStream_t stream) {
  const float* x    = (const float*)d_in[0];
  const float* Wl   = (const float*)d_in[1];
  const float* Wr   = (const float*)d_in[2];
  const float* att  = (const float*)d_in[3];
  const float* bias = (const float*)d_in[4];
  float* out = (float*)d_out;

  float* xl  = (float*)d_ws;                       // N x 384
  float* xr  = xl + (size_t)N_NODES * HC;          // N x 384
  float* sqv = xr + (size_t)N_NODES * HC;          // N
  int*   idx = (int*)(sqv + N_NODES);              // N x 16

  sq_kernel<<<N_NODES / 4, 256, 0, stream>>>(x, sqv);
  gemm_xw<<<dim3(N_NODES / 64, 3, 2), 256, 0, stream>>>(x, Wl, Wr, xl, xr);
  knn_kernel<<<N_NODES / 64, 512, 0, stream>>>(x, sqv, idx);
  attn_kernel<<<N_NODES, 64, 0, stream>>>(xl, xr, att, bias, idx, out);
}

// Round 4
// 1223.119 us; speedup vs baseline: 1.7170x; 1.7170x over previous
//
#include <hip/hip_runtime.h>
#include <math.h>

#define N_NODES 16384
#define DIM 128
#define HC 384          // HEADS * C
#define NEG_SLOPE 0.2f
#define KNN 16
#define KN_CAP 8

typedef _Float16 f16x8 __attribute__((ext_vector_type(8)));
typedef _Float16 f16x2 __attribute__((ext_vector_type(2)));
typedef float f32x4 __attribute__((ext_vector_type(4)));

// ---------------- prep 1: sq + split x into f16 hi/lo ----------------
__global__ __launch_bounds__(256) void prep_x(const float* __restrict__ x,
                                              float* __restrict__ sq,
                                              _Float16* __restrict__ xhi,
                                              _Float16* __restrict__ xlo) {
  const int wv = threadIdx.x >> 6;
  const int lane = threadIdx.x & 63;
  const int row = blockIdx.x * 4 + wv;
  const float2 v = *(const float2*)&x[row * DIM + lane * 2];
  float s = v.x * v.x + v.y * v.y;
  #pragma unroll
  for (int off = 32; off > 0; off >>= 1) s += __shfl_down(s, off);
  _Float16 h0 = (_Float16)v.x, h1 = (_Float16)v.y;
  _Float16 l0 = (_Float16)(v.x - (float)h0), l1 = (_Float16)(v.y - (float)h1);
  f16x2 hh; hh[0] = h0; hh[1] = h1;
  f16x2 ll; ll[0] = l0; ll[1] = l1;
  *(f16x2*)&xhi[row * DIM + lane * 2] = hh;
  *(f16x2*)&xlo[row * DIM + lane * 2] = ll;
  if (lane == 0) sq[row] = s;
}

// ---------------- prep 2: W transpose + split (WT[c][k]) ----------------
__global__ __launch_bounds__(256) void prep_w(const float* __restrict__ Wl,
                                              const float* __restrict__ Wr,
                                              _Float16* __restrict__ wthi,   // [2][384*128]
                                              _Float16* __restrict__ wtlo) {
  const int t = blockIdx.x * 256 + threadIdx.x;   // [0, 98304)
  const int mat = t / 49152;
  const int e = t - mat * 49152;                  // e = k*384 + c
  const int k = e / HC;
  const int c = e - k * HC;
  const float w = (mat ? Wr : Wl)[e];
  _Float16 h = (_Float16)w;
  _Float16 l = (_Float16)(w - (float)h);
  wthi[mat * 49152 + c * DIM + k] = h;
  wtlo[mat * 49152 + c * DIM + k] = l;
}

// ---------------- kernel: xl = x@Wl, xr = x@Wr via MFMA f16-split ----------------
__global__ __launch_bounds__(256) void gemm_xw_mfma(const _Float16* __restrict__ xhi,
                                                    const _Float16* __restrict__ xlo,
                                                    const _Float16* __restrict__ wthi,
                                                    const _Float16* __restrict__ wtlo,
                                                    _Float16* __restrict__ xl,
                                                    _Float16* __restrict__ xr) {
  const int lane = threadIdx.x & 63;
  const int t = blockIdx.x * 4 + (threadIdx.x >> 6);  // [0, 49152)
  const int mat = t / 24576;
  const int rem = t - mat * 24576;
  const int rt = rem / 24;
  const int ct = rem - rt * 24;
  const int r0 = lane & 15;
  const int g8 = (lane >> 4) * 8;
  const _Float16* ap_hi = xhi + (size_t)(rt * 16 + r0) * DIM + g8;
  const _Float16* ap_lo = xlo + (size_t)(rt * 16 + r0) * DIM + g8;
  const _Float16* bp_hi = wthi + mat * 49152 + (ct * 16 + r0) * DIM + g8;
  const _Float16* bp_lo = wtlo + mat * 49152 + (ct * 16 + r0) * DIM + g8;
  f32x4 acc = {0.f, 0.f, 0.f, 0.f};
  #pragma unroll
  for (int ks = 0; ks < 4; ks++) {
    f16x8 ah = *(const f16x8*)(ap_hi + ks * 32);
    f16x8 al = *(const f16x8*)(ap_lo + ks * 32);
    f16x8 bh = *(const f16x8*)(bp_hi + ks * 32);
    f16x8 bl = *(const f16x8*)(bp_lo + ks * 32);
    acc = __builtin_amdgcn_mfma_f32_16x16x32_f16(ah, bh, acc, 0, 0, 0);
    acc = __builtin_amdgcn_mfma_f32_16x16x32_f16(ah, bl, acc, 0, 0, 0);
    acc = __builtin_amdgcn_mfma_f32_16x16x32_f16(al, bh, acc, 0, 0, 0);
  }
  _Float16* o = mat ? xr : xl;
  #pragma unroll
  for (int i = 0; i < 4; i++) {
    const int row = rt * 16 + (lane >> 4) * 4 + i;
    o[(size_t)row * HC + ct * 16 + r0] = (_Float16)acc[i];
  }
}

// ---------------- knn: MFMA pairwise-dot + fused top-16 ----------------
__device__ __forceinline__ void knn_tile(
    int tile, int tid, int lane, int wv, int rowbase, int r0, int g8, int rb4,
    const _Float16* __restrict__ xhi, const _Float16* __restrict__ xlo,
    const float* __restrict__ sq,
    const f16x8 (&ahi)[4][4], const f16x8 (&alo)[4][4], const f32x4 (&srv)[4],
    float* Thr, int* Cnt, float (*Topd)[64], int (*Topi)[64],
    float (*Bufd)[64], int (*Bufi)[64], int* Flag,
    int& kcnt, float& wd, int& wj, int& wpos) {
  const int colbase = tile * 128;
  const int cg = colbase + wv * 16 + r0;

  // B fragments straight from global (L2-hot: all blocks stream same cols)
  f16x8 bh[4], bl[4];
  const size_t bb = (size_t)cg * DIM + g8;
  #pragma unroll
  for (int ks = 0; ks < 4; ks++) {
    bh[ks] = *(const f16x8*)&xhi[bb + ks * 32];
    bl[ks] = *(const f16x8*)&xlo[bb + ks * 32];
  }
  const float nsc2 = -0.5f * sq[cg];

  f32x4 acc[4];
  #pragma unroll
  for (int rt = 0; rt < 4; rt++) {
    acc[rt][0] = nsc2; acc[rt][1] = nsc2; acc[rt][2] = nsc2; acc[rt][3] = nsc2;
  }
  #pragma unroll
  for (int rt = 0; rt < 4; rt++) {
    #pragma unroll
    for (int ks = 0; ks < 4; ks++) {
      acc[rt] = __builtin_amdgcn_mfma_f32_16x16x32_f16(ahi[rt][ks], bh[ks], acc[rt], 0, 0, 0);
      acc[rt] = __builtin_amdgcn_mfma_f32_16x16x32_f16(ahi[rt][ks], bl[ks], acc[rt], 0, 0, 0);
      acc[rt] = __builtin_amdgcn_mfma_f32_16x16x32_f16(alo[rt][ks], bh[ks], acc[rt], 0, 0, 0);
    }
  }
  // acc = dot - sc/2;  d = sr + sc - 2*dot = sr - 2*acc;  cand: d<=thr <=> acc >= (sr-thr)/2
  unsigned pend = 0;
  #pragma unroll
  for (int rt = 0; rt < 4; rt++)
    #pragma unroll
    for (int i = 0; i < 4; i++) {
      const int rg = rowbase + rt * 16 + rb4 + i;
      if (cg != rg) pend |= (1u << (rt * 4 + i));
    }

  while (true) {
    f32x4 thrv[4];
    #pragma unroll
    for (int rt = 0; rt < 4; rt++) thrv[rt] = *(const f32x4*)&Thr[rt * 16 + rb4];
    #pragma unroll
    for (int rt = 0; rt < 4; rt++)
      #pragma unroll
      for (int i = 0; i < 4; i++) {
        const unsigned b = 1u << (rt * 4 + i);
        if ((pend & b) && !(acc[rt][i] >= (srv[rt][i] - thrv[rt][i]) * 0.5f)) pend &= ~b;
      }
    const int anyc = __syncthreads_count(pend != 0);
    if (anyc == 0) break;
    if (tid == 0) *Flag = 0;
    __syncthreads();  // B1: reset visible before pushes
    if (pend) {
      #pragma unroll
      for (int rt = 0; rt < 4; rt++)
        #pragma unroll
        for (int i = 0; i < 4; i++) {
          const unsigned b = 1u << (rt * 4 + i);
          if (pend & b) {
            const int r = rt * 16 + rb4 + i;
            const int slot = atomicAdd(&Cnt[r], 1);
            if (slot < KN_CAP) {
              Bufd[slot][r] = srv[rt][i] - 2.0f * acc[rt][i];
              Bufi[slot][r] = cg;
              pend &= ~b;
            }
          }
        }
      if (pend) *Flag = 1;
    }
    __syncthreads();  // B2: pushes + flag visible
    const int fl = *Flag;
    if (tid < 64) {
      int nn = Cnt[tid]; if (nn > KN_CAP) nn = KN_CAP;
      for (int e = 0; e < nn; e++) {
        const float d = Bufd[e][tid];
        const int jj = Bufi[e][tid];
        bool rescan = false;
        if (kcnt < KNN) {
          Topd[kcnt][tid] = d; Topi[kcnt][tid] = jj; kcnt++;
          rescan = (kcnt == KNN);
        } else if (d < wd || (d == wd && jj < wj)) {
          Topd[wpos][tid] = d; Topi[wpos][tid] = jj;
          rescan = true;
        }
        if (rescan) {  // recompute lexicographic-max (worst) of the 16
          wd = Topd[0][tid]; wj = Topi[0][tid]; wpos = 0;
          #pragma unroll
          for (int e2 = 1; e2 < KNN; e2++) {
            const float dd = Topd[e2][tid];
            const int j2 = Topi[e2][tid];
            if (dd > wd || (dd == wd && j2 > wj)) { wd = dd; wj = j2; wpos = e2; }
          }
          Thr[tid] = wd;
        }
      }
      Cnt[tid] = 0;
    }
    __syncthreads();  // B3: merge/Thr visible; orders fl-read vs next reset
    if (!fl) break;
  }
}

__global__ __launch_bounds__(512, 2) void knn_kernel(const _Float16* __restrict__ xhi,
                                                     const _Float16* __restrict__ xlo,
                                                     const float* __restrict__ sq,
                                                     int* __restrict__ idxo) {
  __shared__ float Thr[64];
  __shared__ int Cnt[64];
  __shared__ float Topd[KNN][64];
  __shared__ int   Topi[KNN][64];
  __shared__ float Bufd[KN_CAP][64];
  __shared__ int   Bufi[KN_CAP][64];
  __shared__ int Flag;

  const int tid = threadIdx.x;
  const int lane = tid & 63;
  const int wv = __builtin_amdgcn_readfirstlane(tid >> 6);
  const int rowbase = blockIdx.x * 64;
  const int r0 = lane & 15;
  const int g8 = (lane >> 4) * 8;
  const int rb4 = (lane >> 4) * 4;

  // A fragments: all 64 rows of the block, hi+lo, in registers (128 VGPR)
  f16x8 ahi[4][4], alo[4][4];
  #pragma unroll
  for (int rt = 0; rt < 4; rt++) {
    const size_t ab = (size_t)(rowbase + rt * 16 + r0) * DIM + g8;
    #pragma unroll
    for (int ks = 0; ks < 4; ks++) {
      ahi[rt][ks] = *(const f16x8*)&xhi[ab + ks * 32];
      alo[rt][ks] = *(const f16x8*)&xlo[ab + ks * 32];
    }
  }
  f32x4 srv[4];
  #pragma unroll
  for (int rt = 0; rt < 4; rt++) srv[rt] = *(const f32x4*)&sq[rowbase + rt * 16 + rb4];

  if (tid < 64) {
    Thr[tid] = __builtin_inff();
    Cnt[tid] = 0;
  }
  if (tid == 0) Flag = 0;
  __syncthreads();

  int kcnt = 0, wj = 0, wpos = 0;
  float wd = __builtin_inff();

  for (int tile = 0; tile < N_NODES / 128; tile++) {
    knn_tile(tile, tid, lane, wv, rowbase, r0, g8, rb4, xhi, xlo, sq,
             ahi, alo, srv, Thr, Cnt, Topd, Topi, Bufd, Bufi, &Flag,
             kcnt, wd, wj, wpos);
  }

  if (tid < 64) {
    #pragma unroll
    for (int e = 0; e < KNN; e++)
      idxo[(rowbase + tid) * KNN + e] = Topi[e][tid];
  }
}

// ---------------- attention epilogue ----------------
__global__ __launch_bounds__(64) void attn_kernel(const _Float16* __restrict__ xl,
                                                  const _Float16* __restrict__ xr,
                                                  const float* __restrict__ att,
                                                  const float* __restrict__ bias,
                                                  const int* __restrict__ idxo,
                                                  float* __restrict__ out) {
  const int n = blockIdx.x;
  const int lane = threadIdx.x;
  __shared__ int nb[KNN];
  if (lane < KNN) nb[lane] = idxo[n * KNN + lane];
  __syncthreads();
  float o0 = 0.f, o1 = 0.f;
  #pragma unroll
  for (int h = 0; h < 3; h++) {
    const float r0 = (float)xr[(size_t)n * HC + h * 128 + lane];
    const float r1 = (float)xr[(size_t)n * HC + h * 128 + 64 + lane];
    const float a0 = att[h * 128 + lane];
    const float a1 = att[h * 128 + 64 + lane];
    float v0[KNN], v1[KNN], e[KNN];
    #pragma unroll
    for (int kk = 0; kk < KNN; kk++) {
      const _Float16* xp = &xl[(size_t)nb[kk] * HC + h * 128];
      float x0 = (float)xp[lane], x1 = (float)xp[64 + lane];
      v0[kk] = x0; v1[kk] = x1;
      float g0 = x0 + r0; g0 = g0 >= 0.f ? g0 : NEG_SLOPE * g0;
      float g1 = x1 + r1; g1 = g1 >= 0.f ? g1 : NEG_SLOPE * g1;
      float p = a0 * g0 + a1 * g1;
      #pragma unroll
      for (int off = 32; off > 0; off >>= 1) p += __shfl_xor(p, off);
      e[kk] = p;
    }
    float m = e[0];
    #pragma unroll
    for (int kk = 1; kk < KNN; kk++) m = fmaxf(m, e[kk]);
    float s = 0.f;
    float w[KNN];
    #pragma unroll
    for (int kk = 0; kk < KNN; kk++) { w[kk] = expf(e[kk] - m); s += w[kk]; }
    #pragma unroll
    for (int kk = 0; kk < KNN; kk++) {
      float al = w[kk] / s;
      o0 += al * v0[kk];
      o1 += al * v1[kk];
    }
  }
  out[n * 128 + lane]      = o0 / 3.f + bias[lane];
  out[n * 128 + 64 + lane] = o1 / 3.f + bias[64 + lane];
}

extern "C" void kernel_launch(void* const* d_in, const int* in_sizes, int n_in,
                              void* d_out, int out_size, void* d_ws, size_t ws_size,
                              hipStream_t stream) {
  const float* x    = (const float*)d_in[0];
  const float* Wl   = (const float*)d_in[1];
  const float* Wr   = (const float*)d_in[2];
  const float* att  = (const float*)d_in[3];
  const float* bias = (const float*)d_in[4];
  float* out = (float*)d_out;

  _Float16* xhi  = (_Float16*)d_ws;                    // N*128
  _Float16* xlo  = xhi + (size_t)N_NODES * DIM;        // N*128
  _Float16* wthi = xlo + (size_t)N_NODES * DIM;        // 2*384*128
  _Float16* wtlo = wthi + 2 * HC * DIM;
  _Float16* xl   = wtlo + 2 * HC * DIM;                // N*384
  _Float16* xr   = xl + (size_t)N_NODES * HC;          // N*384
  float*    sqv  = (float*)(xr + (size_t)N_NODES * HC);
  int*      idx  = (int*)(sqv + N_NODES);              // N*16

  prep_x<<<N_NODES / 4, 256, 0, stream>>>(x, sqv, xhi, xlo);
  prep_w<<<384, 256, 0, stream>>>(Wl, Wr, wthi, wtlo);
  gemm_xw_mfma<<<12288, 256, 0, stream>>>(xhi, xlo, wthi, wtlo, xl, xr);
  knn_kernel<<<N_NODES / 64, 512, 0, stream>>>(xhi, xlo, sqv, idx);
  attn_kernel<<<N_NODES, 64, 0, stream>>>(xl, xr, att, bias, idx, out);
}

// Round 5
// 1108.683 us; speedup vs baseline: 1.8942x; 1.1032x over previous
//
#include <hip/hip_runtime.h>
#include <math.h>

#define N_NODES 16384
#define DIM 128
#define HC 384          // HEADS * C
#define NEG_SLOPE 0.2f
#define KNN 16
#define KP 20           // approx candidate pool per row
#define KCAP 10         // per-round push buffer capacity

typedef _Float16 f16x8 __attribute__((ext_vector_type(8)));
typedef _Float16 f16x2 __attribute__((ext_vector_type(2)));
typedef float f32x4 __attribute__((ext_vector_type(4)));

__device__ __forceinline__ void barrier_lds() {
  asm volatile("s_waitcnt lgkmcnt(0)" ::: "memory");
  __builtin_amdgcn_s_barrier();
}

// ---------------- prep 1: sq + split x into f16 hi/lo ----------------
__global__ __launch_bounds__(256) void prep_x(const float* __restrict__ x,
                                              float* __restrict__ sq,
                                              _Float16* __restrict__ xhi,
                                              _Float16* __restrict__ xlo) {
  const int wv = threadIdx.x >> 6;
  const int lane = threadIdx.x & 63;
  const int row = blockIdx.x * 4 + wv;
  const float2 v = *(const float2*)&x[row * DIM + lane * 2];
  float s = v.x * v.x + v.y * v.y;
  #pragma unroll
  for (int off = 32; off > 0; off >>= 1) s += __shfl_down(s, off);
  _Float16 h0 = (_Float16)v.x, h1 = (_Float16)v.y;
  _Float16 l0 = (_Float16)(v.x - (float)h0), l1 = (_Float16)(v.y - (float)h1);
  f16x2 hh; hh[0] = h0; hh[1] = h1;
  f16x2 ll; ll[0] = l0; ll[1] = l1;
  *(f16x2*)&xhi[row * DIM + lane * 2] = hh;
  *(f16x2*)&xlo[row * DIM + lane * 2] = ll;
  if (lane == 0) sq[row] = s;
}

// ---------------- prep 2: W transpose + split (WT[c][k]) ----------------
__global__ __launch_bounds__(256) void prep_w(const float* __restrict__ Wl,
                                              const float* __restrict__ Wr,
                                              _Float16* __restrict__ wthi,
                                              _Float16* __restrict__ wtlo) {
  const int t = blockIdx.x * 256 + threadIdx.x;   // [0, 98304)
  const int mat = t / 49152;
  const int e = t - mat * 49152;                  // e = k*384 + c
  const int k = e / HC;
  const int c = e - k * HC;
  const float w = (mat ? Wr : Wl)[e];
  _Float16 h = (_Float16)w;
  _Float16 l = (_Float16)(w - (float)h);
  wthi[mat * 49152 + c * DIM + k] = h;
  wtlo[mat * 49152 + c * DIM + k] = l;
}

// ---------------- xl = x@Wl, xr = x@Wr via MFMA f16-split ----------------
__global__ __launch_bounds__(256) void gemm_xw_mfma(const _Float16* __restrict__ xhi,
                                                    const _Float16* __restrict__ xlo,
                                                    const _Float16* __restrict__ wthi,
                                                    const _Float16* __restrict__ wtlo,
                                                    _Float16* __restrict__ xl,
                                                    _Float16* __restrict__ xr) {
  const int lane = threadIdx.x & 63;
  const int t = blockIdx.x * 4 + (threadIdx.x >> 6);  // [0, 49152)
  const int mat = t / 24576;
  const int rem = t - mat * 24576;
  const int rt = rem / 24;
  const int ct = rem - rt * 24;
  const int r0 = lane & 15;
  const int g8 = (lane >> 4) * 8;
  const _Float16* ap_hi = xhi + (size_t)(rt * 16 + r0) * DIM + g8;
  const _Float16* ap_lo = xlo + (size_t)(rt * 16 + r0) * DIM + g8;
  const _Float16* bp_hi = wthi + mat * 49152 + (ct * 16 + r0) * DIM + g8;
  const _Float16* bp_lo = wtlo + mat * 49152 + (ct * 16 + r0) * DIM + g8;
  f32x4 acc = {0.f, 0.f, 0.f, 0.f};
  #pragma unroll
  for (int ks = 0; ks < 4; ks++) {
    f16x8 ah = *(const f16x8*)(ap_hi + ks * 32);
    f16x8 al = *(const f16x8*)(ap_lo + ks * 32);
    f16x8 bh = *(const f16x8*)(bp_hi + ks * 32);
    f16x8 bl = *(const f16x8*)(bp_lo + ks * 32);
    acc = __builtin_amdgcn_mfma_f32_16x16x32_f16(ah, bh, acc, 0, 0, 0);
    acc = __builtin_amdgcn_mfma_f32_16x16x32_f16(ah, bl, acc, 0, 0, 0);
    acc = __builtin_amdgcn_mfma_f32_16x16x32_f16(al, bh, acc, 0, 0, 0);
  }
  _Float16* o = mat ? xr : xl;
  #pragma unroll
  for (int i = 0; i < 4; i++) {
    const int row = rt * 16 + (lane >> 4) * 4 + i;
    o[(size_t)row * HC + ct * 16 + r0] = (_Float16)acc[i];
  }
}

// ---------------- knn: hi-only MFMA + batched top-20 ----------------
// 512 thr (8 waves), grid 256 (1 block/CU). Wave wv owns cols wv*16+r0 of each
// 128-col tile; 2 tiles per batch; B-frags + sq prefetched one batch ahead.
__global__ __launch_bounds__(512, 2) void knn_kernel(const _Float16* __restrict__ xhi,
                                                     const float* __restrict__ sq,
                                                     int* __restrict__ cand) {
  __shared__ __align__(16) float Thr[64];
  __shared__ int Cnt[64];
  __shared__ float Topd[KP][64];
  __shared__ int   Topi[KP][64];
  __shared__ float Bufd[KCAP][64];
  __shared__ int   Bufi[KCAP][64];
  __shared__ int Flag;

  const int tid = threadIdx.x;
  const int lane = tid & 63;
  const int wv = __builtin_amdgcn_readfirstlane(tid >> 6);
  const int rowbase = blockIdx.x * 64;
  const int r0 = lane & 15;
  const int g8 = (lane >> 4) * 8;
  const int rb4 = (lane >> 4) * 4;

  // A fragments (hi only): 64 rows of the block in registers
  f16x8 ahi[4][4];
  #pragma unroll
  for (int rt = 0; rt < 4; rt++) {
    const size_t ab = (size_t)(rowbase + rt * 16 + r0) * DIM + g8;
    #pragma unroll
    for (int ks = 0; ks < 4; ks++) ahi[rt][ks] = *(const f16x8*)&xhi[ab + ks * 32];
  }
  f32x4 srv[4];
  #pragma unroll
  for (int rt = 0; rt < 4; rt++) srv[rt] = *(const f32x4*)&sq[rowbase + rt * 16 + rb4];

  if (tid < 64) { Thr[tid] = __builtin_inff(); Cnt[tid] = 0; }
  if (tid == 0) Flag = 0;
  __syncthreads();

  int kcnt = 0, wj = 0, wpos = 0;
  float wd = __builtin_inff();

  const int NB = N_NODES / 256;  // 64 batches (2 x 128-col tiles each)
  const int cbase = wv * 16 + r0;

  // preload batch 0
  f16x8 bcur[2][4]; float scur[2];
  #pragma unroll
  for (int tt = 0; tt < 2; tt++) {
    const int cg = tt * 128 + cbase;
    const size_t bb = (size_t)cg * DIM + g8;
    #pragma unroll
    for (int ks = 0; ks < 4; ks++) bcur[tt][ks] = *(const f16x8*)&xhi[bb + ks * 32];
    scur[tt] = sq[cg];
  }

  for (int b = 0; b < NB; b++) {
    // prefetch batch b+1 (wraps to 0 on last iter; unused)
    const int bn = (b + 1 < NB) ? b + 1 : 0;
    f16x8 bnx[2][4]; float snx[2];
    #pragma unroll
    for (int tt = 0; tt < 2; tt++) {
      const int cg = bn * 256 + tt * 128 + cbase;
      const size_t bb = (size_t)cg * DIM + g8;
      #pragma unroll
      for (int ks = 0; ks < 4; ks++) bnx[tt][ks] = *(const f16x8*)&xhi[bb + ks * 32];
      snx[tt] = sq[cg];
    }

    // MFMA: acc = dot - sc/2
    f32x4 acc[2][4];
    #pragma unroll
    for (int tt = 0; tt < 2; tt++) {
      const float iv = -0.5f * scur[tt];
      #pragma unroll
      for (int rt = 0; rt < 4; rt++) {
        acc[tt][rt][0] = iv; acc[tt][rt][1] = iv; acc[tt][rt][2] = iv; acc[tt][rt][3] = iv;
        #pragma unroll
        for (int ks = 0; ks < 4; ks++)
          acc[tt][rt] = __builtin_amdgcn_mfma_f32_16x16x32_f16(ahi[rt][ks], bcur[tt][ks],
                                                               acc[tt][rt], 0, 0, 0);
      }
    }

    // d = sr - 2*acc (approx); mark non-self
    unsigned pend = 0;
    #pragma unroll
    for (int tt = 0; tt < 2; tt++) {
      const int cg = b * 256 + tt * 128 + cbase;
      #pragma unroll
      for (int rt = 0; rt < 4; rt++)
        #pragma unroll
        for (int i = 0; i < 4; i++) {
          const int rg = rowbase + rt * 16 + rb4 + i;
          acc[tt][rt][i] = srv[rt][i] - 2.0f * acc[tt][rt][i];
          if (cg != rg) pend |= (1u << (tt * 16 + rt * 4 + i));
        }
    }

    // push/merge rounds (LDS-only sync: raw barrier + lgkmcnt)
    while (true) {
      f32x4 thrv[4];
      #pragma unroll
      for (int rt = 0; rt < 4; rt++) thrv[rt] = *(const f32x4*)&Thr[rt * 16 + rb4];
      #pragma unroll
      for (int tt = 0; tt < 2; tt++)
        #pragma unroll
        for (int rt = 0; rt < 4; rt++)
          #pragma unroll
          for (int i = 0; i < 4; i++) {
            const unsigned bb2 = 1u << (tt * 16 + rt * 4 + i);
            if ((pend & bb2) && !(acc[tt][rt][i] <= thrv[rt][i])) pend &= ~bb2;
          }
      if (tid == 0) Flag = 0;
      barrier_lds();  // B1: reset visible
      if (pend) {
        #pragma unroll
        for (int tt = 0; tt < 2; tt++) {
          const int cg = b * 256 + tt * 128 + cbase;
          #pragma unroll
          for (int rt = 0; rt < 4; rt++)
            #pragma unroll
            for (int i = 0; i < 4; i++) {
              const unsigned bb2 = 1u << (tt * 16 + rt * 4 + i);
              if (pend & bb2) {
                const int r = rt * 16 + rb4 + i;
                const int slot = atomicAdd(&Cnt[r], 1);
                if (slot < KCAP) {
                  Bufd[slot][r] = acc[tt][rt][i];
                  Bufi[slot][r] = cg;
                  pend &= ~bb2;
                }
              }
            }
        }
        if (pend) Flag = 1;
      }
      barrier_lds();  // B2: pushes + flag visible
      const int fl = Flag;
      if (tid < 64) {
        int nn = Cnt[tid]; if (nn > KCAP) nn = KCAP;
        for (int e = 0; e < nn; e++) {
          const float d = Bufd[e][tid];
          const int jj = Bufi[e][tid];
          bool rescan = false;
          if (kcnt < KP) {
            Topd[kcnt][tid] = d; Topi[kcnt][tid] = jj; kcnt++;
            rescan = (kcnt == KP);
          } else if (d < wd || (d == wd && jj < wj)) {
            Topd[wpos][tid] = d; Topi[wpos][tid] = jj;
            rescan = true;
          }
          if (rescan) {
            wd = Topd[0][tid]; wj = Topi[0][tid]; wpos = 0;
            #pragma unroll
            for (int e2 = 1; e2 < KP; e2++) {
              const float dd = Topd[e2][tid];
              const int j2 = Topi[e2][tid];
              if (dd > wd || (dd == wd && j2 > wj)) { wd = dd; wj = j2; wpos = e2; }
            }
            Thr[tid] = wd;
          }
        }
        Cnt[tid] = 0;
      }
      barrier_lds();  // B3: merge/Thr visible
      if (!fl) break;
    }

    // rotate prefetch
    #pragma unroll
    for (int tt = 0; tt < 2; tt++) {
      #pragma unroll
      for (int ks = 0; ks < 4; ks++) bcur[tt][ks] = bnx[tt][ks];
      scur[tt] = snx[tt];
    }
  }

  if (tid < 64) {
    #pragma unroll
    for (int e = 0; e < KP; e++)
      cand[(rowbase + tid) * KP + e] = Topi[e][tid];
  }
}

// ---------------- refine: exact f32 re-rank of the 20 candidates ----------------
__global__ __launch_bounds__(256) void refine_kernel(const float* __restrict__ x,
                                                     const float* __restrict__ sq,
                                                     const int* __restrict__ cand,
                                                     int* __restrict__ idxo) {
  const int wv = threadIdx.x >> 6;
  const int lane = threadIdx.x & 63;
  const int row = blockIdx.x * 4 + wv;
  const bool act = lane < KP;
  int c = 0;
  float d = __builtin_inff();
  if (act) {
    c = cand[row * KP + lane];
    const float4* xr4 = (const float4*)&x[(size_t)row * DIM];
    const float4* xc4 = (const float4*)&x[(size_t)c * DIM];
    float dot = 0.f;
    #pragma unroll
    for (int i = 0; i < 32; i++) {
      const float4 a = xr4[i], bb = xc4[i];
      dot += a.x * bb.x + a.y * bb.y + a.z * bb.z + a.w * bb.w;
    }
    d = sq[row] + sq[c] - 2.0f * dot;
  }
  int rank = 0;
  #pragma unroll
  for (int m = 0; m < KP; m++) {
    const float dm = __shfl(d, m);
    const int cm = __shfl(c, m);
    rank += ((dm < d) || (dm == d && cm < c)) ? 1 : 0;
  }
  if (act && rank < KNN) idxo[row * KNN + rank] = c;
}

// ---------------- attention epilogue ----------------
__global__ __launch_bounds__(64) void attn_kernel(const _Float16* __restrict__ xl,
                                                  const _Float16* __restrict__ xr,
                                                  const float* __restrict__ att,
                                                  const float* __restrict__ bias,
                                                  const int* __restrict__ idxo,
                                                  float* __restrict__ out) {
  const int n = blockIdx.x;
  const int lane = threadIdx.x;
  __shared__ int nb[KNN];
  if (lane < KNN) nb[lane] = idxo[n * KNN + lane];
  __syncthreads();
  float o0 = 0.f, o1 = 0.f;
  #pragma unroll
  for (int h = 0; h < 3; h++) {
    const float r0 = (float)xr[(size_t)n * HC + h * 128 + lane];
    const float r1 = (float)xr[(size_t)n * HC + h * 128 + 64 + lane];
    const float a0 = att[h * 128 + lane];
    const float a1 = att[h * 128 + 64 + lane];
    float v0[KNN], v1[KNN], e[KNN];
    #pragma unroll
    for (int kk = 0; kk < KNN; kk++) {
      const _Float16* xp = &xl[(size_t)nb[kk] * HC + h * 128];
      float x0 = (float)xp[lane], x1 = (float)xp[64 + lane];
      v0[kk] = x0; v1[kk] = x1;
      float g0 = x0 + r0; g0 = g0 >= 0.f ? g0 : NEG_SLOPE * g0;
      float g1 = x1 + r1; g1 = g1 >= 0.f ? g1 : NEG_SLOPE * g1;
      float p = a0 * g0 + a1 * g1;
      #pragma unroll
      for (int off = 32; off > 0; off >>= 1) p += __shfl_xor(p, off);
      e[kk] = p;
    }
    float m = e[0];
    #pragma unroll
    for (int kk = 1; kk < KNN; kk++) m = fmaxf(m, e[kk]);
    float s = 0.f;
    float w[KNN];
    #pragma unroll
    for (int kk = 0; kk < KNN; kk++) { w[kk] = expf(e[kk] - m); s += w[kk]; }
    #pragma unroll
    for (int kk = 0; kk < KNN; kk++) {
      float al = w[kk] / s;
      o0 += al * v0[kk];
      o1 += al * v1[kk];
    }
  }
  out[n * 128 + lane]      = o0 / 3.f + bias[lane];
  out[n * 128 + 64 + lane] = o1 / 3.f + bias[64 + lane];
}

extern "C" void kernel_launch(void* const* d_in, const int* in_sizes, int n_in,
                              void* d_out, int out_size, void* d_ws, size_t ws_size,
                              hipStream_t stream) {
  const float* x    = (const float*)d_in[0];
  const float* Wl   = (const float*)d_in[1];
  const float* Wr   = (const float*)d_in[2];
  const float* att  = (const float*)d_in[3];
  const float* bias = (const float*)d_in[4];
  float* out = (float*)d_out;

  _Float16* xhi  = (_Float16*)d_ws;                    // N*128
  _Float16* xlo  = xhi + (size_t)N_NODES * DIM;        // N*128
  _Float16* wthi = xlo + (size_t)N_NODES * DIM;        // 2*384*128
  _Float16* wtlo = wthi + 2 * HC * DIM;
  _Float16* xl   = wtlo + 2 * HC * DIM;                // N*384
  _Float16* xr   = xl + (size_t)N_NODES * HC;          // N*384
  float*    sqv  = (float*)(xr + (size_t)N_NODES * HC);
  int*      cnd  = (int*)(sqv + N_NODES);              // N*20
  int*      idx  = cnd + (size_t)N_NODES * KP;         // N*16

  prep_x<<<N_NODES / 4, 256, 0, stream>>>(x, sqv, xhi, xlo);
  prep_w<<<384, 256, 0, stream>>>(Wl, Wr, wthi, wtlo);
  gemm_xw_mfma<<<12288, 256, 0, stream>>>(xhi, xlo, wthi, wtlo, xl, xr);
  knn_kernel<<<N_NODES / 64, 512, 0, stream>>>(xhi, sqv, cnd);
  refine_kernel<<<N_NODES / 4, 256, 0, stream>>>(x, sqv, cnd, idx);
  attn_kernel<<<N_NODES, 64, 0, stream>>>(xl, xr, att, bias, idx, out);
}